// Round 3
// baseline (406.052 us; speedup 1.0000x reference)
//
#include <hip/hip_runtime.h>
#include <hip/hip_bf16.h>

// Problem constants (fixed by the reference)
#define S_LEN 2048
#define NH    16
#define HD    64
#define EMB   1024
#define BATCH 2
#define M_TOT 4096   // B*S

typedef __attribute__((ext_vector_type(8))) __bf16 bf16x8;
typedef __attribute__((ext_vector_type(4))) __bf16 bf16x4;
typedef __attribute__((ext_vector_type(4))) float  f32x4;

// ---------------------------------------------------------------------------
// fp32 -> bf16 cast, vectorized 4-wide
// ---------------------------------------------------------------------------
__global__ __launch_bounds__(256) void cast_kernel(const float* __restrict__ in,
                                                   __bf16* __restrict__ out, int n4) {
    int i = blockIdx.x * 256 + threadIdx.x;
    if (i < n4) {
        f32x4 v = ((const f32x4*)in)[i];
        bf16x4 o;
        o[0] = (__bf16)v[0]; o[1] = (__bf16)v[1];
        o[2] = (__bf16)v[2]; o[3] = (__bf16)v[3];
        ((bf16x4*)out)[i] = o;
    }
}

// ---------------------------------------------------------------------------
// Fused QKV projection GEMM.
// C[M=4096, N=1024] = A[M,K=1024] @ W[N,K]^T + bias
// blockIdx.z selects {Q,K,V}. Q,K stored [B,H,S,D] bf16. V stored [B,H,D,S]
// (transposed) so the attention PV B-operand is a contiguous 16B read.
// 128x128 tile, 4 waves (2x2), each wave 64x64 = 4x4 frags of 16x16x32 MFMA.
// LDS padded to [128][72] (144B rows = 36 dwords -> 2-way bank alias = free,
// and 16B-aligned for ds_read_b128).
// ---------------------------------------------------------------------------
__global__ __launch_bounds__(256) void gemm_qkv(const __bf16* __restrict__ A,
        const __bf16* __restrict__ Wq, const __bf16* __restrict__ Wk,
        const __bf16* __restrict__ Wv,
        const float* __restrict__ bq, const float* __restrict__ bk,
        const float* __restrict__ bv,
        __bf16* __restrict__ Qo, __bf16* __restrict__ Ko, __bf16* __restrict__ Vo) {
    __shared__ __bf16 As[128][72];
    __shared__ __bf16 Bs[128][72];

    const int z = blockIdx.z;
    const __bf16* Bw   = (z == 0) ? Wq : (z == 1) ? Wk : Wv;
    const float*  bias = (z == 0) ? bq : (z == 1) ? bk : bv;
    __bf16*       outp = (z == 0) ? Qo : (z == 1) ? Ko : Vo;

    const int tid  = threadIdx.x;
    const int wid  = tid >> 6;
    const int lane = tid & 63;
    const int lrow = lane & 15;
    const int lhi  = lane >> 4;
    const int m0 = blockIdx.y * 128;
    const int n0 = blockIdx.x * 128;
    const int wr = wid >> 1, wc = wid & 1;

    f32x4 acc[4][4];
#pragma unroll
    for (int i = 0; i < 4; ++i)
#pragma unroll
        for (int j = 0; j < 4; ++j)
            acc[i][j] = (f32x4){0.f, 0.f, 0.f, 0.f};

    const int sr = tid >> 3;          // 0..31
    const int sc = (tid & 7) * 8;     // 0..56

    for (int k0 = 0; k0 < EMB; k0 += 64) {
#pragma unroll
        for (int it = 0; it < 4; ++it) {
            int row = it * 32 + sr;
            *(bf16x8*)&As[row][sc] = *(const bf16x8*)&A [(size_t)(m0 + row) * EMB + k0 + sc];
            *(bf16x8*)&Bs[row][sc] = *(const bf16x8*)&Bw[(size_t)(n0 + row) * EMB + k0 + sc];
        }
        __syncthreads();
#pragma unroll
        for (int kk = 0; kk < 2; ++kk) {
            bf16x8 af[4], bfr[4];
#pragma unroll
            for (int i = 0; i < 4; ++i)
                af[i] = *(const bf16x8*)&As[wr * 64 + i * 16 + lrow][kk * 32 + lhi * 8];
#pragma unroll
            for (int j = 0; j < 4; ++j)
                bfr[j] = *(const bf16x8*)&Bs[wc * 64 + j * 16 + lrow][kk * 32 + lhi * 8];
#pragma unroll
            for (int i = 0; i < 4; ++i)
#pragma unroll
                for (int j = 0; j < 4; ++j)
                    acc[i][j] = __builtin_amdgcn_mfma_f32_16x16x32_bf16(af[i], bfr[j], acc[i][j], 0, 0, 0);
        }
        __syncthreads();
    }

    // Epilogue: C/D layout col = lane&15, row = (lane>>4)*4 + reg  [m89-verified]
#pragma unroll
    for (int i = 0; i < 4; ++i) {
#pragma unroll
        for (int j = 0; j < 4; ++j) {
#pragma unroll
            for (int jj = 0; jj < 4; ++jj) {
                int row = m0 + wr * 64 + i * 16 + lhi * 4 + jj;   // token index b*S+s
                int col = n0 + wc * 64 + j * 16 + lrow;           // feature e = h*64+d
                float v = acc[i][j][jj] + bias[col];
                int b = row >> 11, s = row & (S_LEN - 1);
                int h = col >> 6,  d = col & (HD - 1);
                size_t idx = (z == 2)
                    ? ((size_t)(b * NH + h) * HD + d) * S_LEN + s     // V^T: [B,H,D,S]
                    : ((size_t)(b * NH + h) * S_LEN + s) * HD + d;    // Q,K: [B,H,S,D]
                outp[idx] = (__bf16)v;
            }
        }
    }
}

// ---------------------------------------------------------------------------
// Output projection GEMM: out[M,1024] fp32 = ctx[M,1024]bf16 @ Wo[1024,1024]^T + bo
// ---------------------------------------------------------------------------
__global__ __launch_bounds__(256) void gemm_out(const __bf16* __restrict__ A,
        const __bf16* __restrict__ Bw, const float* __restrict__ bias,
        float* __restrict__ outp) {
    __shared__ __bf16 As[128][72];
    __shared__ __bf16 Bs[128][72];

    const int tid  = threadIdx.x;
    const int wid  = tid >> 6;
    const int lane = tid & 63;
    const int lrow = lane & 15;
    const int lhi  = lane >> 4;
    const int m0 = blockIdx.y * 128;
    const int n0 = blockIdx.x * 128;
    const int wr = wid >> 1, wc = wid & 1;

    f32x4 acc[4][4];
#pragma unroll
    for (int i = 0; i < 4; ++i)
#pragma unroll
        for (int j = 0; j < 4; ++j)
            acc[i][j] = (f32x4){0.f, 0.f, 0.f, 0.f};

    const int sr = tid >> 3;
    const int sc = (tid & 7) * 8;

    for (int k0 = 0; k0 < EMB; k0 += 64) {
#pragma unroll
        for (int it = 0; it < 4; ++it) {
            int row = it * 32 + sr;
            *(bf16x8*)&As[row][sc] = *(const bf16x8*)&A [(size_t)(m0 + row) * EMB + k0 + sc];
            *(bf16x8*)&Bs[row][sc] = *(const bf16x8*)&Bw[(size_t)(n0 + row) * EMB + k0 + sc];
        }
        __syncthreads();
#pragma unroll
        for (int kk = 0; kk < 2; ++kk) {
            bf16x8 af[4], bfr[4];
#pragma unroll
            for (int i = 0; i < 4; ++i)
                af[i] = *(const bf16x8*)&As[wr * 64 + i * 16 + lrow][kk * 32 + lhi * 8];
#pragma unroll
            for (int j = 0; j < 4; ++j)
                bfr[j] = *(const bf16x8*)&Bs[wc * 64 + j * 16 + lrow][kk * 32 + lhi * 8];
#pragma unroll
            for (int i = 0; i < 4; ++i)
#pragma unroll
                for (int j = 0; j < 4; ++j)
                    acc[i][j] = __builtin_amdgcn_mfma_f32_16x16x32_bf16(af[i], bfr[j], acc[i][j], 0, 0, 0);
        }
        __syncthreads();
    }

#pragma unroll
    for (int i = 0; i < 4; ++i)
#pragma unroll
        for (int j = 0; j < 4; ++j)
#pragma unroll
            for (int jj = 0; jj < 4; ++jj) {
                int row = m0 + wr * 64 + i * 16 + lhi * 4 + jj;
                int col = n0 + wc * 64 + j * 16 + lrow;
                outp[(size_t)row * EMB + col] = acc[i][j][jj] + bias[col];
            }
}

// ---------------------------------------------------------------------------
// Flash attention (causal). Grid: (S/64, B*H). 4 waves/block, each wave owns a
// 16-row q-tile. 32-key steps. K/V read straight from global (per-head K+V =
// 512KB -> L2-resident; guide common-mistake #7). V is pre-transposed [B,H,D,S].
// Score C-frag: row=(lane>>4)*4+reg (q-row), col=lane&15 (key). P goes through
// a per-wave LDS buffer to re-shape into the PV A-operand layout.
// ---------------------------------------------------------------------------
__global__ __launch_bounds__(256) void attn_kernel(const __bf16* __restrict__ Q,
        const __bf16* __restrict__ K, const __bf16* __restrict__ Vt,
        __bf16* __restrict__ ctx) {
    __shared__ __bf16 Plds[4][16][32];

    const int wid  = threadIdx.x >> 6;
    const int lane = threadIdx.x & 63;
    const int lrow = lane & 15, lhi = lane >> 4;
    const int bh = blockIdx.y;                     // b*NH + h
    const int q0 = blockIdx.x * 64 + wid * 16;

    const __bf16* Qh = Q  + (size_t)bh * S_LEN * HD;
    const __bf16* Kh = K  + (size_t)bh * S_LEN * HD;
    const __bf16* Vh = Vt + (size_t)bh * HD * S_LEN;

    // Q fragments: A[row=lane&15][k=(lane>>4)*8 ..+8], two 32-wide d-chunks
    bf16x8 qf[2];
#pragma unroll
    for (int dc = 0; dc < 2; ++dc)
        qf[dc] = *(const bf16x8*)&Qh[(size_t)(q0 + lrow) * HD + dc * 32 + lhi * 8];

    f32x4 o[4];
#pragma unroll
    for (int db = 0; db < 4; ++db) o[db] = (f32x4){0.f, 0.f, 0.f, 0.f};
    float mrow[4], lsum[4];
#pragma unroll
    for (int jj = 0; jj < 4; ++jj) { mrow[jj] = -1e30f; lsum[jj] = 0.f; }

    const int nkt = (q0 + 16 + 31) >> 5;           // 32-key tiles needed (causal)
    for (int kt = 0; kt < nkt; ++kt) {
        const int kk0 = kt * 32;

        // K B-fragments: B[k=d][col=key] = K[key][d] — contiguous in [S,D]
        bf16x8 kf[2][2];
#pragma unroll
        for (int kb = 0; kb < 2; ++kb)
#pragma unroll
            for (int dc = 0; dc < 2; ++dc)
                kf[kb][dc] = *(const bf16x8*)&Kh[(size_t)(kk0 + kb * 16 + lrow) * HD + dc * 32 + lhi * 8];

        f32x4 sc[2];
#pragma unroll
        for (int kb = 0; kb < 2; ++kb) {
            sc[kb] = __builtin_amdgcn_mfma_f32_16x16x32_bf16(qf[0], kf[kb][0], (f32x4){0.f,0.f,0.f,0.f}, 0, 0, 0);
            sc[kb] = __builtin_amdgcn_mfma_f32_16x16x32_bf16(qf[1], kf[kb][1], sc[kb], 0, 0, 0);
        }

        // mask (key<=row keeps) then scale by 1/sqrt(64)
        float val[2][4];
        const int rowb = q0 + lhi * 4;
#pragma unroll
        for (int kb = 0; kb < 2; ++kb) {
            int key = kk0 + kb * 16 + lrow;
#pragma unroll
            for (int jj = 0; jj < 4; ++jj)
                val[kb][jj] = (key <= rowb + jj) ? sc[kb][jj] * 0.125f : -1e30f;
        }

        // row max across the 16 lanes of this lhi-group
        float pm[4];
#pragma unroll
        for (int jj = 0; jj < 4; ++jj) {
            pm[jj] = fmaxf(val[0][jj], val[1][jj]);
#pragma unroll
            for (int m = 1; m <= 8; m <<= 1)
                pm[jj] = fmaxf(pm[jj], __shfl_xor(pm[jj], m));
        }

        // online-softmax update + P -> LDS (bf16)
        float f[4];
#pragma unroll
        for (int jj = 0; jj < 4; ++jj) {
            float mn = fmaxf(mrow[jj], pm[jj]);
            f[jj] = __expf(mrow[jj] - mn);
            float p0 = __expf(val[0][jj] - mn);
            float p1 = __expf(val[1][jj] - mn);
            Plds[wid][lhi * 4 + jj][lrow]      = (__bf16)p0;
            Plds[wid][lhi * 4 + jj][16 + lrow] = (__bf16)p1;
            float s2 = p0 + p1;
#pragma unroll
            for (int m = 1; m <= 8; m <<= 1)
                s2 += __shfl_xor(s2, m);
            lsum[jj] = lsum[jj] * f[jj] + s2;
            mrow[jj] = mn;
        }
#pragma unroll
        for (int db = 0; db < 4; ++db)
#pragma unroll
            for (int jj = 0; jj < 4; ++jj)
                o[db][jj] *= f[jj];

        // DS ops are in-order per wave; defensive drain before cross-lane read
        asm volatile("s_waitcnt lgkmcnt(0)" ::: "memory");
        __builtin_amdgcn_sched_barrier(0);
        bf16x8 pa = *(const bf16x8*)&Plds[wid][lrow][lhi * 8];

        // PV: B[k=key][col=d] = Vt[d][key] — contiguous in [D,S]
#pragma unroll
        for (int db = 0; db < 4; ++db) {
            bf16x8 vf = *(const bf16x8*)&Vh[(size_t)(db * 16 + lrow) * S_LEN + kk0 + lhi * 8];
            o[db] = __builtin_amdgcn_mfma_f32_16x16x32_bf16(pa, vf, o[db], 0, 0, 0);
        }
    }

    // normalize + write ctx (merged-head [B,S,E] bf16 for the output GEMM)
    const int b = bh >> 4, h = bh & 15;
#pragma unroll
    for (int jj = 0; jj < 4; ++jj) {
        float inv = 1.f / lsum[jj];
        size_t row = (size_t)b * S_LEN + q0 + lhi * 4 + jj;
#pragma unroll
        for (int db = 0; db < 4; ++db)
            ctx[row * EMB + h * HD + db * 16 + lrow] = (__bf16)(o[db][jj] * inv);
    }
}

// ---------------------------------------------------------------------------
extern "C" void kernel_launch(void* const* d_in, const int* in_sizes, int n_in,
                              void* d_out, int out_size, void* d_ws, size_t ws_size,
                              hipStream_t stream) {
    const float* x  = (const float*)d_in[0];
    const float* Wq = (const float*)d_in[1];
    const float* bq = (const float*)d_in[2];
    const float* Wk = (const float*)d_in[3];
    const float* bk = (const float*)d_in[4];
    const float* Wv = (const float*)d_in[5];
    const float* bv = (const float*)d_in[6];
    const float* Wo = (const float*)d_in[7];
    const float* bo = (const float*)d_in[8];

    char* ws = (char*)d_ws;
    __bf16* xb  = (__bf16*)(ws);                       // 8 MB  (4M bf16)
    __bf16* Wqb = (__bf16*)(ws + ( 8ull << 20));       // 2 MB
    __bf16* Wkb = (__bf16*)(ws + (10ull << 20));
    __bf16* Wvb = (__bf16*)(ws + (12ull << 20));
    __bf16* Wob = (__bf16*)(ws + (14ull << 20));
    __bf16* Qb  = (__bf16*)(ws + (16ull << 20));       // 8 MB [B,H,S,D]
    __bf16* Kb  = (__bf16*)(ws + (24ull << 20));       // 8 MB [B,H,S,D]
    __bf16* Vtb = (__bf16*)(ws + (32ull << 20));       // 8 MB [B,H,D,S]
    __bf16* Cb  = (__bf16*)(ws + (40ull << 20));       // 8 MB [B,S,E]

    // casts
    cast_kernel<<<4096, 256, 0, stream>>>(x,  xb,  1048576);  // 4M/4
    cast_kernel<<<1024, 256, 0, stream>>>(Wq, Wqb, 262144);   // 1M/4
    cast_kernel<<<1024, 256, 0, stream>>>(Wk, Wkb, 262144);
    cast_kernel<<<1024, 256, 0, stream>>>(Wv, Wvb, 262144);
    cast_kernel<<<1024, 256, 0, stream>>>(Wo, Wob, 262144);

    // fused QKV projection (z selects Q/K/V)
    gemm_qkv<<<dim3(EMB / 128, M_TOT / 128, 3), 256, 0, stream>>>(
        xb, Wqb, Wkb, Wvb, bq, bk, bv, Qb, Kb, Vtb);

    // flash attention
    attn_kernel<<<dim3(S_LEN / 64, BATCH * NH), 256, 0, stream>>>(Qb, Kb, Vtb, Cb);

    // output projection (fp32 out + bias)
    gemm_out<<<dim3(EMB / 128, M_TOT / 128), 256, 0, stream>>>(Cb, Wob, bo, (float*)d_out);
}

// Round 5
// 299.876 us; speedup vs baseline: 1.3541x; 1.3541x over previous
//
#include <hip/hip_runtime.h>
#include <hip/hip_bf16.h>

// Problem constants (fixed by the reference)
#define S_LEN 2048
#define NH    16
#define HD    64
#define EMB   1024
#define BATCH 2
#define M_TOT 4096   // B*S

typedef __attribute__((ext_vector_type(8)))  __bf16   bf16x8;
typedef __attribute__((ext_vector_type(4)))  __bf16   bf16x4;
typedef __attribute__((ext_vector_type(4)))  float    f32x4;
typedef __attribute__((ext_vector_type(16))) float    f32x16;
typedef __attribute__((ext_vector_type(4)))  unsigned u32x4;

// pack two f32 -> one u32 of 2 bf16 (compiler emits good code; m240: don't hand-asm)
static __device__ __forceinline__ unsigned pk2(float a, float b) {
    unsigned short ua = __builtin_bit_cast(unsigned short, (__bf16)a);
    unsigned short ub = __builtin_bit_cast(unsigned short, (__bf16)b);
    return (unsigned)ua | ((unsigned)ub << 16);
}

// ---------------------------------------------------------------------------
// fp32 -> bf16 cast, vectorized 4-wide
// ---------------------------------------------------------------------------
__global__ __launch_bounds__(256) void cast_kernel(const float* __restrict__ in,
                                                   __bf16* __restrict__ out, int n4) {
    int i = blockIdx.x * 256 + threadIdx.x;
    if (i < n4) {
        f32x4 v = ((const f32x4*)in)[i];
        bf16x4 o;
        o[0] = (__bf16)v[0]; o[1] = (__bf16)v[1];
        o[2] = (__bf16)v[2]; o[3] = (__bf16)v[3];
        ((bf16x4*)out)[i] = o;
    }
}

// ---------------------------------------------------------------------------
// Fused QKV projection GEMM, m97-style staging: global_load_lds width=16 into
// LINEAR LDS [128][64] (no pad — gload_lds needs contiguous lane-order dest).
// C[4096,1024] = A @ W^T + bias. z selects {Q,K,V}. Q,K -> [B,H,S,D];
// V -> [B,H,D,S] (transposed) for the attention PV A-operand.
// ---------------------------------------------------------------------------
__global__ __launch_bounds__(256) void gemm_qkv(const __bf16* __restrict__ A,
        const __bf16* __restrict__ Wq, const __bf16* __restrict__ Wk,
        const __bf16* __restrict__ Wv,
        const float* __restrict__ bq, const float* __restrict__ bk,
        const float* __restrict__ bv,
        __bf16* __restrict__ Qo, __bf16* __restrict__ Ko, __bf16* __restrict__ Vo) {
    __shared__ __bf16 As[128][64];
    __shared__ __bf16 Bs[128][64];

    const int z = blockIdx.z;
    const __bf16* Bw   = (z == 0) ? Wq : (z == 1) ? Wk : Wv;
    const float*  bias = (z == 0) ? bq : (z == 1) ? bk : bv;
    __bf16*       outp = (z == 0) ? Qo : (z == 1) ? Ko : Vo;

    const int tid  = threadIdx.x;
    const int wid  = tid >> 6;
    const int lane = tid & 63;
    const int lrow = lane & 15;
    const int lhi  = lane >> 4;
    const int m0 = blockIdx.y * 128;
    const int n0 = blockIdx.x * 128;
    const int wr = wid >> 1, wc = wid & 1;

    const int lr8 = lane >> 3;          // 0..7   (row within 8-row chunk)
    const int lc8 = (lane & 7) * 8;     // 0..56  (col elem)

    f32x4 acc[4][4];
#pragma unroll
    for (int i = 0; i < 4; ++i)
#pragma unroll
        for (int j = 0; j < 4; ++j)
            acc[i][j] = (f32x4){0.f, 0.f, 0.f, 0.f};

    for (int k0 = 0; k0 < EMB; k0 += 64) {
        // stage: each wave fills rows [wid*32, wid*32+32) of As and Bs.
        // gload_lds scatters lane l's 16B at ldsbase + l*16 = row +l/8, col (l%8)*8.
#pragma unroll
        for (int t = 0; t < 4; ++t) {
            const int row = wid * 32 + t * 8;
            __builtin_amdgcn_global_load_lds(
                (const __attribute__((address_space(1))) void*)&A[(size_t)(m0 + row + lr8) * EMB + k0 + lc8],
                (__attribute__((address_space(3))) void*)&As[row][0], 16, 0, 0);
            __builtin_amdgcn_global_load_lds(
                (const __attribute__((address_space(1))) void*)&Bw[(size_t)(n0 + row + lr8) * EMB + k0 + lc8],
                (__attribute__((address_space(3))) void*)&Bs[row][0], 16, 0, 0);
        }
        __syncthreads();   // compiler drains vmcnt(0) before barrier
#pragma unroll
        for (int kk = 0; kk < 2; ++kk) {
            bf16x8 af[4], bfr[4];
#pragma unroll
            for (int i = 0; i < 4; ++i)
                af[i] = *(const bf16x8*)&As[wr * 64 + i * 16 + lrow][kk * 32 + lhi * 8];
#pragma unroll
            for (int j = 0; j < 4; ++j)
                bfr[j] = *(const bf16x8*)&Bs[wc * 64 + j * 16 + lrow][kk * 32 + lhi * 8];
#pragma unroll
            for (int i = 0; i < 4; ++i)
#pragma unroll
                for (int j = 0; j < 4; ++j)
                    acc[i][j] = __builtin_amdgcn_mfma_f32_16x16x32_bf16(af[i], bfr[j], acc[i][j], 0, 0, 0);
        }
        __syncthreads();
    }

    // Epilogue: C/D layout col = lane&15, row = (lane>>4)*4 + reg  [m89-verified]
#pragma unroll
    for (int i = 0; i < 4; ++i) {
#pragma unroll
        for (int j = 0; j < 4; ++j) {
#pragma unroll
            for (int jj = 0; jj < 4; ++jj) {
                int row = m0 + wr * 64 + i * 16 + lhi * 4 + jj;   // token b*S+s
                int col = n0 + wc * 64 + j * 16 + lrow;           // feature h*64+d
                float v = acc[i][j][jj] + bias[col];
                int b = row >> 11, s = row & (S_LEN - 1);
                int h = col >> 6,  d = col & (HD - 1);
                size_t idx = (z == 2)
                    ? ((size_t)(b * NH + h) * HD + d) * S_LEN + s     // V^T: [B,H,D,S]
                    : ((size_t)(b * NH + h) * S_LEN + s) * HD + d;    // Q,K: [B,H,S,D]
                outp[idx] = (__bf16)v;
            }
        }
    }
}

// ---------------------------------------------------------------------------
// Output projection: out[4096,1024] fp32 = ctx bf16 @ Wo^T + bo (same staging)
// ---------------------------------------------------------------------------
__global__ __launch_bounds__(256) void gemm_out(const __bf16* __restrict__ A,
        const __bf16* __restrict__ Bw, const float* __restrict__ bias,
        float* __restrict__ outp) {
    __shared__ __bf16 As[128][64];
    __shared__ __bf16 Bs[128][64];

    const int tid  = threadIdx.x;
    const int wid  = tid >> 6;
    const int lane = tid & 63;
    const int lrow = lane & 15;
    const int lhi  = lane >> 4;
    const int m0 = blockIdx.y * 128;
    const int n0 = blockIdx.x * 128;
    const int wr = wid >> 1, wc = wid & 1;
    const int lr8 = lane >> 3;
    const int lc8 = (lane & 7) * 8;

    f32x4 acc[4][4];
#pragma unroll
    for (int i = 0; i < 4; ++i)
#pragma unroll
        for (int j = 0; j < 4; ++j)
            acc[i][j] = (f32x4){0.f, 0.f, 0.f, 0.f};

    for (int k0 = 0; k0 < EMB; k0 += 64) {
#pragma unroll
        for (int t = 0; t < 4; ++t) {
            const int row = wid * 32 + t * 8;
            __builtin_amdgcn_global_load_lds(
                (const __attribute__((address_space(1))) void*)&A[(size_t)(m0 + row + lr8) * EMB + k0 + lc8],
                (__attribute__((address_space(3))) void*)&As[row][0], 16, 0, 0);
            __builtin_amdgcn_global_load_lds(
                (const __attribute__((address_space(1))) void*)&Bw[(size_t)(n0 + row + lr8) * EMB + k0 + lc8],
                (__attribute__((address_space(3))) void*)&Bs[row][0], 16, 0, 0);
        }
        __syncthreads();
#pragma unroll
        for (int kk = 0; kk < 2; ++kk) {
            bf16x8 af[4], bfr[4];
#pragma unroll
            for (int i = 0; i < 4; ++i)
                af[i] = *(const bf16x8*)&As[wr * 64 + i * 16 + lrow][kk * 32 + lhi * 8];
#pragma unroll
            for (int j = 0; j < 4; ++j)
                bfr[j] = *(const bf16x8*)&Bs[wc * 64 + j * 16 + lrow][kk * 32 + lhi * 8];
#pragma unroll
            for (int i = 0; i < 4; ++i)
#pragma unroll
                for (int j = 0; j < 4; ++j)
                    acc[i][j] = __builtin_amdgcn_mfma_f32_16x16x32_bf16(af[i], bfr[j], acc[i][j], 0, 0, 0);
        }
        __syncthreads();
    }

#pragma unroll
    for (int i = 0; i < 4; ++i)
#pragma unroll
        for (int j = 0; j < 4; ++j)
#pragma unroll
            for (int jj = 0; jj < 4; ++jj) {
                int row = m0 + wr * 64 + i * 16 + lhi * 4 + jj;
                int col = n0 + wc * 64 + j * 16 + lrow;
                outp[(size_t)row * EMB + col] = acc[i][j][jj] + bias[col];
            }
}

// ---------------------------------------------------------------------------
// Flash attention (causal), swapped-QK^T 32x32 in-register softmax.
// Grid (S/128, B*H), 4 waves/block; each wave owns 32 q-rows, steps 32 keys.
// S^T = mfma_32x32x16(K_frag, Q_frag): lane holds q-col = lane&31, 16 keys at
// row=(reg&3)+8*(reg>>2)+4*(lane>>5)  [m74/m101-verified C/D layout].
// Softmax fully in-register: 15 in-lane fmax + 1 shfl_xor(32); P packed to
// bf16 pairs and redistributed with 4 shfl_xor(32) into the PV B-fragment.
// O^T accumulated in-register; epilogue transposes via per-wave LDS tile.
// No __syncthreads anywhere. K/V read direct from L2-resident global.
// ---------------------------------------------------------------------------
__global__ __launch_bounds__(256) void attn_kernel(const __bf16* __restrict__ Q,
        const __bf16* __restrict__ K, const __bf16* __restrict__ Vt,
        __bf16* __restrict__ ctx) {
    __shared__ __bf16 Ol[4][32][72];

    const int wid  = threadIdx.x >> 6;
    const int lane = threadIdx.x & 63;
    const int lq   = lane & 31;          // q-column owned by this lane
    const int hi   = lane >> 5;          // half-select
    const int bh   = blockIdx.y;         // b*NH + h
    const int q0w  = blockIdx.x * 128 + wid * 32;

    const __bf16* Qh = Q  + (size_t)bh * S_LEN * HD;
    const __bf16* Kh = K  + (size_t)bh * S_LEN * HD;
    const __bf16* Vh = Vt + (size_t)bh * HD * S_LEN;

    // Q B-frag (col=lq, k-elems hi*8..+8 within each 16-d slice), pre-scaled by
    // 1/sqrt(64)=2^-3 (exact in bf16).
    bf16x8 qf[4];
#pragma unroll
    for (int ds = 0; ds < 4; ++ds) {
        bf16x8 t = *(const bf16x8*)&Qh[(size_t)(q0w + lq) * HD + ds * 16 + hi * 8];
#pragma unroll
        for (int j = 0; j < 8; ++j) qf[ds][j] = (__bf16)((float)t[j] * 0.125f);
    }

    f32x16 o0 = {0}, o1 = {0};           // O^T accum, d-blocks 0..31 / 32..63
#pragma unroll
    for (int r = 0; r < 16; ++r) { o0[r] = 0.f; o1[r] = 0.f; }
    float m = -1e30f, l = 0.f;

    const int nkt = q0w / 32 + 1;        // causal: keys up to q0w+31
    for (int kt = 0; kt < nkt; ++kt) {
        const int kk0 = kt * 32;

        // K A-frag: row=key=lq, k-elems hi*8..+8 per 16-d slice
        f32x16 s = {0};
#pragma unroll
        for (int r = 0; r < 16; ++r) s[r] = 0.f;
#pragma unroll
        for (int ds = 0; ds < 4; ++ds) {
            bf16x8 kf = *(const bf16x8*)&Kh[(size_t)(kk0 + lq) * HD + ds * 16 + hi * 8];
            s = __builtin_amdgcn_mfma_f32_32x32x16_bf16(kf, qf[ds], s, 0, 0, 0);
        }

        // causal mask — only the diagonal tile needs it (wave-uniform branch)
        if (kk0 == q0w) {
#pragma unroll
            for (int r = 0; r < 16; ++r) {
                int keyl = (r & 3) + 8 * (r >> 2) + 4 * hi;
                s[r] = (keyl <= lq) ? s[r] : -1e30f;
            }
        }

        // row max: 15 in-lane + cross-half exchange
        float pm = s[0];
#pragma unroll
        for (int r = 1; r < 16; ++r) pm = fmaxf(pm, s[r]);
        pm = fmaxf(pm, __shfl_xor(pm, 32));

        float mn = fmaxf(m, pm);
        float f  = __expf(m - mn);
        m = mn;

        float ps = 0.f;
#pragma unroll
        for (int r = 0; r < 16; ++r) { s[r] = __expf(s[r] - mn); ps += s[r]; }
        ps += __shfl_xor(ps, 32);
        l = l * f + ps;

#pragma unroll
        for (int r = 0; r < 16; ++r) { o0[r] *= f; o1[r] *= f; }

        // pack P to bf16 pairs: w[i] = keys {2i,2i+1} of this lane's key-set
        unsigned w0 = pk2(s[0],  s[1]),  w1 = pk2(s[2],  s[3]);
        unsigned w2 = pk2(s[4],  s[5]),  w3 = pk2(s[6],  s[7]);
        unsigned w4 = pk2(s[8],  s[9]),  w5 = pk2(s[10], s[11]);
        unsigned w6 = pk2(s[12], s[13]), w7 = pk2(s[14], s[15]);

        // cross-half redistribution into PV B-frag (col=lq, k=(hi)*8+j):
        // slice0 (keys 0-15):  hi0 needs {w0,w1, hi1.w0,hi1.w1}; hi1 {hi0.w2,hi0.w3, w2,w3}
        // slice1 (keys 16-31): hi0 needs {w4,w5, hi1.w4,hi1.w5}; hi1 {hi0.w6,hi0.w7, w6,w7}
        unsigned e0 = (unsigned)__shfl_xor((int)(hi ? w0 : w2), 32);
        unsigned e1 = (unsigned)__shfl_xor((int)(hi ? w1 : w3), 32);
        unsigned e2 = (unsigned)__shfl_xor((int)(hi ? w4 : w6), 32);
        unsigned e3 = (unsigned)__shfl_xor((int)(hi ? w5 : w7), 32);
        u32x4 pb0, pb1;
        if (hi) { pb0 = (u32x4){e0, e1, w2, w3}; pb1 = (u32x4){e2, e3, w6, w7}; }
        else    { pb0 = (u32x4){w0, w1, e0, e1}; pb1 = (u32x4){w4, w5, e2, e3}; }
        bf16x8 pb0b = __builtin_bit_cast(bf16x8, pb0);
        bf16x8 pb1b = __builtin_bit_cast(bf16x8, pb1);

        // PV: O^T[d][q] += V^T[d][k] * P^T[k][q]; A = V^T frag (row=d-local=lq)
        {
            bf16x8 va = *(const bf16x8*)&Vh[(size_t)(lq) * S_LEN + kk0 + hi * 8];
            bf16x8 vb = *(const bf16x8*)&Vh[(size_t)(lq) * S_LEN + kk0 + 16 + hi * 8];
            o0 = __builtin_amdgcn_mfma_f32_32x32x16_bf16(va, pb0b, o0, 0, 0, 0);
            o0 = __builtin_amdgcn_mfma_f32_32x32x16_bf16(vb, pb1b, o0, 0, 0, 0);
        }
        {
            bf16x8 va = *(const bf16x8*)&Vh[(size_t)(32 + lq) * S_LEN + kk0 + hi * 8];
            bf16x8 vb = *(const bf16x8*)&Vh[(size_t)(32 + lq) * S_LEN + kk0 + 16 + hi * 8];
            o1 = __builtin_amdgcn_mfma_f32_32x32x16_bf16(va, pb0b, o1, 0, 0, 0);
            o1 = __builtin_amdgcn_mfma_f32_32x32x16_bf16(vb, pb1b, o1, 0, 0, 0);
        }
    }

    // epilogue: normalize, transpose O^T -> row-major via per-wave LDS tile
    float inv = 1.f / l;
#pragma unroll
    for (int r = 0; r < 16; ++r) {
        int d0 = (r & 3) + 8 * (r >> 2) + 4 * hi;
        Ol[wid][lq][d0]      = (__bf16)(o0[r] * inv);
        Ol[wid][lq][32 + d0] = (__bf16)(o1[r] * inv);
    }
    asm volatile("s_waitcnt lgkmcnt(0)" ::: "memory");
    __builtin_amdgcn_sched_barrier(0);

    const int b = bh >> 4, h = bh & 15;
#pragma unroll
    for (int p = 0; p < 4; ++p) {
        int q  = (lane >> 3) + p * 8;
        int d8 = (lane & 7) * 8;
        bf16x8 v = *(const bf16x8*)&Ol[wid][q][d8];
        *(bf16x8*)&ctx[((size_t)b * S_LEN + q0w + q) * EMB + h * HD + d8] = v;
    }
}

// ---------------------------------------------------------------------------
extern "C" void kernel_launch(void* const* d_in, const int* in_sizes, int n_in,
                              void* d_out, int out_size, void* d_ws, size_t ws_size,
                              hipStream_t stream) {
    const float* x  = (const float*)d_in[0];
    const float* Wq = (const float*)d_in[1];
    const float* bq = (const float*)d_in[2];
    const float* Wk = (const float*)d_in[3];
    const float* bk = (const float*)d_in[4];
    const float* Wv = (const float*)d_in[5];
    const float* bv = (const float*)d_in[6];
    const float* Wo = (const float*)d_in[7];
    const float* bo = (const float*)d_in[8];

    char* ws = (char*)d_ws;
    __bf16* xb  = (__bf16*)(ws);                       // 8 MB  (4M bf16)
    __bf16* Wqb = (__bf16*)(ws + ( 8ull << 20));       // 2 MB
    __bf16* Wkb = (__bf16*)(ws + (10ull << 20));
    __bf16* Wvb = (__bf16*)(ws + (12ull << 20));
    __bf16* Wob = (__bf16*)(ws + (14ull << 20));
    __bf16* Qb  = (__bf16*)(ws + (16ull << 20));       // 8 MB [B,H,S,D]
    __bf16* Kb  = (__bf16*)(ws + (24ull << 20));       // 8 MB [B,H,S,D]
    __bf16* Vtb = (__bf16*)(ws + (32ull << 20));       // 8 MB [B,H,D,S]
    __bf16* Cb  = (__bf16*)(ws + (40ull << 20));       // 8 MB [B,S,E]

    // casts
    cast_kernel<<<4096, 256, 0, stream>>>(x,  xb,  1048576);
    cast_kernel<<<1024, 256, 0, stream>>>(Wq, Wqb, 262144);
    cast_kernel<<<1024, 256, 0, stream>>>(Wk, Wkb, 262144);
    cast_kernel<<<1024, 256, 0, stream>>>(Wv, Wvb, 262144);
    cast_kernel<<<1024, 256, 0, stream>>>(Wo, Wob, 262144);

    // fused QKV projection (z selects Q/K/V)
    gemm_qkv<<<dim3(EMB / 128, M_TOT / 128, 3), 256, 0, stream>>>(
        xb, Wqb, Wkb, Wvb, bq, bk, bv, Qb, Kb, Vtb);

    // flash attention (swapped-QK^T 32x32)
    attn_kernel<<<dim3(S_LEN / 128, BATCH * NH), 256, 0, stream>>>(Qb, Kb, Vtb, Cb);

    // output projection (fp32 out + bias)
    gemm_out<<<dim3(EMB / 128, M_TOT / 128), 256, 0, stream>>>(Cb, Wob, bo, (float*)d_out);
}

// Round 6
// 256.006 us; speedup vs baseline: 1.5861x; 1.1714x over previous
//
#include <hip/hip_runtime.h>
#include <hip/hip_bf16.h>

// Problem constants (fixed by the reference)
#define S_LEN 2048
#define NH    16
#define HD    64
#define EMB   1024
#define BATCH 2
#define M_TOT 4096   // B*S

typedef __attribute__((ext_vector_type(8)))  __bf16   bf16x8;
typedef __attribute__((ext_vector_type(4)))  __bf16   bf16x4;
typedef __attribute__((ext_vector_type(4)))  float    f32x4;
typedef __attribute__((ext_vector_type(16))) float    f32x16;
typedef __attribute__((ext_vector_type(4)))  unsigned u32x4;

// pack two f32 -> one u32 of 2 bf16 (compiler emits good code; m240: don't hand-asm)
static __device__ __forceinline__ unsigned pk2(float a, float b) {
    unsigned short ua = __builtin_bit_cast(unsigned short, (__bf16)a);
    unsigned short ub = __builtin_bit_cast(unsigned short, (__bf16)b);
    return (unsigned)ua | ((unsigned)ub << 16);
}

// ---------------------------------------------------------------------------
// One fused fp32->bf16 cast for x + all 4 weights (one launch instead of 5).
// Region layout: [0,1M) float4 = x; then 4x 256K float4 = Wq,Wk,Wv,Wo.
// ---------------------------------------------------------------------------
__global__ __launch_bounds__(256) void cast_all(const float* __restrict__ x,
        const float* __restrict__ wq, const float* __restrict__ wk,
        const float* __restrict__ wv, const float* __restrict__ wo,
        __bf16* __restrict__ xb, __bf16* __restrict__ wqb,
        __bf16* __restrict__ wkb, __bf16* __restrict__ wvb,
        __bf16* __restrict__ wob) {
    int i = blockIdx.x * 256 + threadIdx.x;           // 0 .. 2M-1
    const float* src; __bf16* dst; int j;
    if (i < (1 << 20)) { src = x; dst = xb; j = i; }
    else {
        int t = i - (1 << 20);
        int r = t >> 18;                              // 0..3
        j = t & ((1 << 18) - 1);
        src = (r == 0) ? wq : (r == 1) ? wk : (r == 2) ? wv : wo;
        dst = (r == 0) ? wqb : (r == 1) ? wkb : (r == 2) ? wvb : wob;
    }
    f32x4 v = ((const f32x4*)src)[j];
    bf16x4 o;
    o[0] = (__bf16)v[0]; o[1] = (__bf16)v[1];
    o[2] = (__bf16)v[2]; o[3] = (__bf16)v[3];
    ((bf16x4*)dst)[j] = o;
}

// ---------------------------------------------------------------------------
// Fused QKV projection GEMM, m97-style staging: global_load_lds width=16 into
// LINEAR LDS [128][64]. C[4096,1024] = A @ W^T + bias. z selects {Q,K,V}.
// Q,K -> [B,H,S,D]; V -> [B,H,D,S] (transposed) for attention PV A-operand.
// ---------------------------------------------------------------------------
__global__ __launch_bounds__(256) void gemm_qkv(const __bf16* __restrict__ A,
        const __bf16* __restrict__ Wq, const __bf16* __restrict__ Wk,
        const __bf16* __restrict__ Wv,
        const float* __restrict__ bq, const float* __restrict__ bk,
        const float* __restrict__ bv,
        __bf16* __restrict__ Qo, __bf16* __restrict__ Ko, __bf16* __restrict__ Vo) {
    __shared__ __bf16 As[128][64];
    __shared__ __bf16 Bs[128][64];

    const int z = blockIdx.z;
    const __bf16* Bw   = (z == 0) ? Wq : (z == 1) ? Wk : Wv;
    const float*  bias = (z == 0) ? bq : (z == 1) ? bk : bv;
    __bf16*       outp = (z == 0) ? Qo : (z == 1) ? Ko : Vo;

    const int tid  = threadIdx.x;
    const int wid  = tid >> 6;
    const int lane = tid & 63;
    const int lrow = lane & 15;
    const int lhi  = lane >> 4;
    const int m0 = blockIdx.y * 128;
    const int n0 = blockIdx.x * 128;
    const int wr = wid >> 1, wc = wid & 1;

    const int lr8 = lane >> 3;          // 0..7   (row within 8-row chunk)
    const int lc8 = (lane & 7) * 8;     // 0..56  (col elem)

    f32x4 acc[4][4];
#pragma unroll
    for (int i = 0; i < 4; ++i)
#pragma unroll
        for (int j = 0; j < 4; ++j)
            acc[i][j] = (f32x4){0.f, 0.f, 0.f, 0.f};

    for (int k0 = 0; k0 < EMB; k0 += 64) {
#pragma unroll
        for (int t = 0; t < 4; ++t) {
            const int row = wid * 32 + t * 8;
            __builtin_amdgcn_global_load_lds(
                (const __attribute__((address_space(1))) void*)&A[(size_t)(m0 + row + lr8) * EMB + k0 + lc8],
                (__attribute__((address_space(3))) void*)&As[row][0], 16, 0, 0);
            __builtin_amdgcn_global_load_lds(
                (const __attribute__((address_space(1))) void*)&Bw[(size_t)(n0 + row + lr8) * EMB + k0 + lc8],
                (__attribute__((address_space(3))) void*)&Bs[row][0], 16, 0, 0);
        }
        __syncthreads();
#pragma unroll
        for (int kk = 0; kk < 2; ++kk) {
            bf16x8 af[4], bfr[4];
#pragma unroll
            for (int i = 0; i < 4; ++i)
                af[i] = *(const bf16x8*)&As[wr * 64 + i * 16 + lrow][kk * 32 + lhi * 8];
#pragma unroll
            for (int j = 0; j < 4; ++j)
                bfr[j] = *(const bf16x8*)&Bs[wc * 64 + j * 16 + lrow][kk * 32 + lhi * 8];
#pragma unroll
            for (int i = 0; i < 4; ++i)
#pragma unroll
                for (int j = 0; j < 4; ++j)
                    acc[i][j] = __builtin_amdgcn_mfma_f32_16x16x32_bf16(af[i], bfr[j], acc[i][j], 0, 0, 0);
        }
        __syncthreads();
    }

    // Epilogue: C/D layout col = lane&15, row = (lane>>4)*4 + reg  [m89-verified]
#pragma unroll
    for (int i = 0; i < 4; ++i) {
#pragma unroll
        for (int j = 0; j < 4; ++j) {
#pragma unroll
            for (int jj = 0; jj < 4; ++jj) {
                int row = m0 + wr * 64 + i * 16 + lhi * 4 + jj;   // token b*S+s
                int col = n0 + wc * 64 + j * 16 + lrow;           // feature h*64+d
                float v = acc[i][j][jj] + bias[col];
                int b = row >> 11, s = row & (S_LEN - 1);
                int h = col >> 6,  d = col & (HD - 1);
                size_t idx = (z == 2)
                    ? ((size_t)(b * NH + h) * HD + d) * S_LEN + s     // V^T: [B,H,D,S]
                    : ((size_t)(b * NH + h) * S_LEN + s) * HD + d;    // Q,K: [B,H,S,D]
                outp[idx] = (__bf16)v;
            }
        }
    }
}

// ---------------------------------------------------------------------------
// Output projection: out[4096,1024] fp32 = ctx bf16 @ Wo^T + bo (same staging)
// ---------------------------------------------------------------------------
__global__ __launch_bounds__(256) void gemm_out(const __bf16* __restrict__ A,
        const __bf16* __restrict__ Bw, const float* __restrict__ bias,
        float* __restrict__ outp) {
    __shared__ __bf16 As[128][64];
    __shared__ __bf16 Bs[128][64];

    const int tid  = threadIdx.x;
    const int wid  = tid >> 6;
    const int lane = tid & 63;
    const int lrow = lane & 15;
    const int lhi  = lane >> 4;
    const int m0 = blockIdx.y * 128;
    const int n0 = blockIdx.x * 128;
    const int wr = wid >> 1, wc = wid & 1;
    const int lr8 = lane >> 3;
    const int lc8 = (lane & 7) * 8;

    f32x4 acc[4][4];
#pragma unroll
    for (int i = 0; i < 4; ++i)
#pragma unroll
        for (int j = 0; j < 4; ++j)
            acc[i][j] = (f32x4){0.f, 0.f, 0.f, 0.f};

    for (int k0 = 0; k0 < EMB; k0 += 64) {
#pragma unroll
        for (int t = 0; t < 4; ++t) {
            const int row = wid * 32 + t * 8;
            __builtin_amdgcn_global_load_lds(
                (const __attribute__((address_space(1))) void*)&A[(size_t)(m0 + row + lr8) * EMB + k0 + lc8],
                (__attribute__((address_space(3))) void*)&As[row][0], 16, 0, 0);
            __builtin_amdgcn_global_load_lds(
                (const __attribute__((address_space(1))) void*)&Bw[(size_t)(n0 + row + lr8) * EMB + k0 + lc8],
                (__attribute__((address_space(3))) void*)&Bs[row][0], 16, 0, 0);
        }
        __syncthreads();
#pragma unroll
        for (int kk = 0; kk < 2; ++kk) {
            bf16x8 af[4], bfr[4];
#pragma unroll
            for (int i = 0; i < 4; ++i)
                af[i] = *(const bf16x8*)&As[wr * 64 + i * 16 + lrow][kk * 32 + lhi * 8];
#pragma unroll
            for (int j = 0; j < 4; ++j)
                bfr[j] = *(const bf16x8*)&Bs[wc * 64 + j * 16 + lrow][kk * 32 + lhi * 8];
#pragma unroll
            for (int i = 0; i < 4; ++i)
#pragma unroll
                for (int j = 0; j < 4; ++j)
                    acc[i][j] = __builtin_amdgcn_mfma_f32_16x16x32_bf16(af[i], bfr[j], acc[i][j], 0, 0, 0);
        }
        __syncthreads();
    }

#pragma unroll
    for (int i = 0; i < 4; ++i)
#pragma unroll
        for (int j = 0; j < 4; ++j)
#pragma unroll
            for (int jj = 0; jj < 4; ++jj) {
                int row = m0 + wr * 64 + i * 16 + lhi * 4 + jj;
                int col = n0 + wc * 64 + j * 16 + lrow;
                outp[(size_t)row * EMB + col] = acc[i][j][jj] + bias[col];
            }
}

// ---------------------------------------------------------------------------
// Flash attention (causal), swapped-QK^T 32x32 in-register softmax.
// v2 changes vs r5 (structure otherwise identical, r5 passed @absmax 0.0078):
//  * 1D grid 512, XCD-aware decode: bh = (bid&7) + 8*(bid>>7) so all 16
//    blocks of one bh land on one XCD (K/V stay in that XCD's L2).
//  * interleaved q-tile per wave: qt = x + 16*wid — every block holds one
//    long wave, so both resident blocks/CU live the full dispatch
//    (occupancy-over-time ~2x).
//  * software prefetch: iteration top issues current V loads + next K loads;
//    L2 latency hides under QK MFMAs + softmax chain.
// ---------------------------------------------------------------------------
__global__ __launch_bounds__(256) void attn_kernel(const __bf16* __restrict__ Q,
        const __bf16* __restrict__ K, const __bf16* __restrict__ Vt,
        __bf16* __restrict__ ctx) {
    __shared__ __bf16 Ol[4][32][72];

    const int wid  = threadIdx.x >> 6;
    const int lane = threadIdx.x & 63;
    const int lq   = lane & 31;          // q-column owned by this lane
    const int hi   = lane >> 5;          // half-select
    // 1D decode: xcd = bid&7; x = (bid>>3)&15; bh = xcd + 8*(bid>>7)
    const int bid  = blockIdx.x;
    const int xcd  = bid & 7;
    const int rem  = bid >> 3;
    const int xq   = rem & 15;
    const int bh   = xcd + 8 * (rem >> 4);       // 0..31
    const int qt   = xq + 16 * wid;              // 0..63 interleaved
    const int q0w  = qt * 32;

    const __bf16* Qh = Q  + (size_t)bh * S_LEN * HD;
    const __bf16* Kh = K  + (size_t)bh * S_LEN * HD;
    const __bf16* Vh = Vt + (size_t)bh * HD * S_LEN;

    // Q B-frag (col=lq, k-elems hi*8..+8 within each 16-d slice), pre-scaled by
    // 1/sqrt(64)=2^-3 (exact in bf16).
    bf16x8 qf[4];
#pragma unroll
    for (int ds = 0; ds < 4; ++ds) {
        bf16x8 t = *(const bf16x8*)&Qh[(size_t)(q0w + lq) * HD + ds * 16 + hi * 8];
#pragma unroll
        for (int j = 0; j < 8; ++j) qf[ds][j] = (__bf16)((float)t[j] * 0.125f);
    }

    f32x16 o0, o1;                       // O^T accum, d-blocks 0..31 / 32..63
#pragma unroll
    for (int r = 0; r < 16; ++r) { o0[r] = 0.f; o1[r] = 0.f; }
    float m = -1e30f, l = 0.f;

    const int nkt = qt + 1;              // causal: 32-key tiles

    // prologue: K frags for kt=0 (row=key=lq, k-elems hi*8..+8 per 16-d slice)
    bf16x8 kf0, kf1, kf2, kf3;
    {
        const __bf16* kp = &Kh[(size_t)lq * HD + hi * 8];
        kf0 = *(const bf16x8*)(kp);      kf1 = *(const bf16x8*)(kp + 16);
        kf2 = *(const bf16x8*)(kp + 32); kf3 = *(const bf16x8*)(kp + 48);
    }

    for (int kt = 0; kt < nkt; ++kt) {
        const int kk0 = kt * 32;

        // issue current V loads (consumed after softmax — latency hidden)
        bf16x8 va0 = *(const bf16x8*)&Vh[(size_t)lq * S_LEN + kk0 + hi * 8];
        bf16x8 vb0 = *(const bf16x8*)&Vh[(size_t)lq * S_LEN + kk0 + 16 + hi * 8];
        bf16x8 va1 = *(const bf16x8*)&Vh[(size_t)(32 + lq) * S_LEN + kk0 + hi * 8];
        bf16x8 vb1 = *(const bf16x8*)&Vh[(size_t)(32 + lq) * S_LEN + kk0 + 16 + hi * 8];

        // issue NEXT K loads (consumed next iteration; clamped on last)
        const int nk0 = (kt + 1 < nkt ? kt + 1 : kt) * 32;
        bf16x8 nkf0, nkf1, nkf2, nkf3;
        {
            const __bf16* kp = &Kh[(size_t)(nk0 + lq) * HD + hi * 8];
            nkf0 = *(const bf16x8*)(kp);      nkf1 = *(const bf16x8*)(kp + 16);
            nkf2 = *(const bf16x8*)(kp + 32); nkf3 = *(const bf16x8*)(kp + 48);
        }

        // QK^T (swapped): S^T = K-frag x Q-frag
        f32x16 s;
#pragma unroll
        for (int r = 0; r < 16; ++r) s[r] = 0.f;
        s = __builtin_amdgcn_mfma_f32_32x32x16_bf16(kf0, qf[0], s, 0, 0, 0);
        s = __builtin_amdgcn_mfma_f32_32x32x16_bf16(kf1, qf[1], s, 0, 0, 0);
        s = __builtin_amdgcn_mfma_f32_32x32x16_bf16(kf2, qf[2], s, 0, 0, 0);
        s = __builtin_amdgcn_mfma_f32_32x32x16_bf16(kf3, qf[3], s, 0, 0, 0);

        // causal mask — only the diagonal tile needs it (wave-uniform branch)
        if (kk0 == q0w) {
#pragma unroll
            for (int r = 0; r < 16; ++r) {
                int keyl = (r & 3) + 8 * (r >> 2) + 4 * hi;
                s[r] = (keyl <= lq) ? s[r] : -1e30f;
            }
        }

        // row max: 15 in-lane + cross-half exchange
        float pm = s[0];
#pragma unroll
        for (int r = 1; r < 16; ++r) pm = fmaxf(pm, s[r]);
        pm = fmaxf(pm, __shfl_xor(pm, 32));

        float mn = fmaxf(m, pm);
        float f  = __expf(m - mn);
        m = mn;

        float ps = 0.f;
#pragma unroll
        for (int r = 0; r < 16; ++r) { s[r] = __expf(s[r] - mn); ps += s[r]; }
        ps += __shfl_xor(ps, 32);
        l = l * f + ps;

#pragma unroll
        for (int r = 0; r < 16; ++r) { o0[r] *= f; o1[r] *= f; }

        // pack P to bf16 pairs: w[i] = keys {2i,2i+1} of this lane's key-set
        unsigned w0 = pk2(s[0],  s[1]),  w1 = pk2(s[2],  s[3]);
        unsigned w2 = pk2(s[4],  s[5]),  w3 = pk2(s[6],  s[7]);
        unsigned w4 = pk2(s[8],  s[9]),  w5 = pk2(s[10], s[11]);
        unsigned w6 = pk2(s[12], s[13]), w7 = pk2(s[14], s[15]);

        // cross-half redistribution into PV B-frag (col=lq, k=(hi)*8+j)
        unsigned e0 = (unsigned)__shfl_xor((int)(hi ? w0 : w2), 32);
        unsigned e1 = (unsigned)__shfl_xor((int)(hi ? w1 : w3), 32);
        unsigned e2 = (unsigned)__shfl_xor((int)(hi ? w4 : w6), 32);
        unsigned e3 = (unsigned)__shfl_xor((int)(hi ? w5 : w7), 32);
        u32x4 pb0, pb1;
        if (hi) { pb0 = (u32x4){e0, e1, w2, w3}; pb1 = (u32x4){e2, e3, w6, w7}; }
        else    { pb0 = (u32x4){w0, w1, e0, e1}; pb1 = (u32x4){w4, w5, e2, e3}; }
        bf16x8 pb0b = __builtin_bit_cast(bf16x8, pb0);
        bf16x8 pb1b = __builtin_bit_cast(bf16x8, pb1);

        // PV: O^T[d][q] += V^T[d][k] * P^T[k][q]
        o0 = __builtin_amdgcn_mfma_f32_32x32x16_bf16(va0, pb0b, o0, 0, 0, 0);
        o0 = __builtin_amdgcn_mfma_f32_32x32x16_bf16(vb0, pb1b, o0, 0, 0, 0);
        o1 = __builtin_amdgcn_mfma_f32_32x32x16_bf16(va1, pb0b, o1, 0, 0, 0);
        o1 = __builtin_amdgcn_mfma_f32_32x32x16_bf16(vb1, pb1b, o1, 0, 0, 0);

        kf0 = nkf0; kf1 = nkf1; kf2 = nkf2; kf3 = nkf3;
    }

    // epilogue: normalize, transpose O^T -> row-major via per-wave LDS tile
    float inv = 1.f / l;
#pragma unroll
    for (int r = 0; r < 16; ++r) {
        int d0 = (r & 3) + 8 * (r >> 2) + 4 * hi;
        Ol[wid][lq][d0]      = (__bf16)(o0[r] * inv);
        Ol[wid][lq][32 + d0] = (__bf16)(o1[r] * inv);
    }
    asm volatile("s_waitcnt lgkmcnt(0)" ::: "memory");
    __builtin_amdgcn_sched_barrier(0);

    const int b = bh >> 4, h = bh & 15;
#pragma unroll
    for (int p = 0; p < 4; ++p) {
        int q  = (lane >> 3) + p * 8;
        int d8 = (lane & 7) * 8;
        bf16x8 v = *(const bf16x8*)&Ol[wid][q][d8];
        *(bf16x8*)&ctx[((size_t)b * S_LEN + q0w + q) * EMB + h * HD + d8] = v;
    }
}

// ---------------------------------------------------------------------------
extern "C" void kernel_launch(void* const* d_in, const int* in_sizes, int n_in,
                              void* d_out, int out_size, void* d_ws, size_t ws_size,
                              hipStream_t stream) {
    const float* x  = (const float*)d_in[0];
    const float* Wq = (const float*)d_in[1];
    const float* bq = (const float*)d_in[2];
    const float* Wk = (const float*)d_in[3];
    const float* bk = (const float*)d_in[4];
    const float* Wv = (const float*)d_in[5];
    const float* bv = (const float*)d_in[6];
    const float* Wo = (const float*)d_in[7];
    const float* bo = (const float*)d_in[8];

    char* ws = (char*)d_ws;
    __bf16* xb  = (__bf16*)(ws);                       // 8 MB  (4M bf16)
    __bf16* Wqb = (__bf16*)(ws + ( 8ull << 20));       // 2 MB
    __bf16* Wkb = (__bf16*)(ws + (10ull << 20));
    __bf16* Wvb = (__bf16*)(ws + (12ull << 20));
    __bf16* Wob = (__bf16*)(ws + (14ull << 20));
    __bf16* Qb  = (__bf16*)(ws + (16ull << 20));       // 8 MB [B,H,S,D]
    __bf16* Kb  = (__bf16*)(ws + (24ull << 20));       // 8 MB [B,H,S,D]
    __bf16* Vtb = (__bf16*)(ws + (32ull << 20));       // 8 MB [B,H,D,S]
    __bf16* Cb  = (__bf16*)(ws + (40ull << 20));       // 8 MB [B,S,E]

    // one fused cast (x + 4 weights)
    cast_all<<<8192, 256, 0, stream>>>(x, Wq, Wk, Wv, Wo, xb, Wqb, Wkb, Wvb, Wob);

    // fused QKV projection (z selects Q/K/V)
    gemm_qkv<<<dim3(EMB / 128, M_TOT / 128, 3), 256, 0, stream>>>(
        xb, Wqb, Wkb, Wvb, bq, bk, bv, Qb, Kb, Vtb);

    // flash attention (swapped-QK^T 32x32, balanced + prefetch + XCD decode)
    attn_kernel<<<dim3(512), 256, 0, stream>>>(Qb, Kb, Vtb, Cb);

    // output projection (fp32 out + bias)
    gemm_out<<<dim3(EMB / 128, M_TOT / 128), 256, 0, stream>>>(Cb, Wob, bo, (float*)d_out);
}